// Round 2
// baseline (1334.356 us; speedup 1.0000x reference)
//
#include <hip/hip_runtime.h>
#include <cstdint>
#include <cstddef>

#define B_      16
#define N_      4096
#define CFEAT_  64
#define NPOINT_ 1024
#define NSAMPLE_ 32
#define CIN_    67
#define COUT_   128
#define R2_     0.04f

// ---------------- K0: collapse the 3 linear layers (no activation between them)
__global__ __launch_bounds__(256) void k_fuse(
    const float* __restrict__ W1, const float* __restrict__ b1,
    const float* __restrict__ W2, const float* __restrict__ b2,
    const float* __restrict__ W3, const float* __restrict__ b3,
    float* __restrict__ Wt /*[CIN][COUT] transposed*/, float* __restrict__ beff /*[COUT]*/) {
  __shared__ float W21[64][CIN_];
  __shared__ float b21[64];
  int t = threadIdx.x;
  for (int i = t; i < 64 * CIN_; i += 256) {
    int o = i / CIN_, c = i - o * CIN_;
    float s = 0.f;
    for (int j = 0; j < 64; ++j) s = fmaf(W2[o * 64 + j], W1[j * CIN_ + c], s);
    W21[o][c] = s;
  }
  if (t < 64) {
    float s = b2[t];
    for (int j = 0; j < 64; ++j) s = fmaf(W2[t * 64 + j], b1[j], s);
    b21[t] = s;
  }
  __syncthreads();
  for (int i = t; i < COUT_ * CIN_; i += 256) {
    int o = i / CIN_, c = i - o * CIN_;
    float s = 0.f;
    for (int j = 0; j < 64; ++j) s = fmaf(W3[o * 64 + j], W21[j][c], s);
    Wt[c * COUT_ + o] = s;   // store transposed [c][o]
  }
  if (t < COUT_) {
    float s = b3[t];
    for (int j = 0; j < 64; ++j) s = fmaf(W3[t * 64 + j], b21[j], s);
    beff[t] = s;
  }
}

// ---------------- K1: farthest point sampling, 1 block per batch
// Must match XLA numerics: d = (dx*dx + dy*dy) + dz*dz, NO fma contraction,
// argmax = first index of max, dist = fminf(dist, d).
__global__ __launch_bounds__(256) void k_fps(
    const float* __restrict__ xyz,
    float* __restrict__ out_newxyz, float* __restrict__ out_fpsf) {
  int b = blockIdx.x, t = threadIdx.x;
  const float* X = xyz + (size_t)b * (N_ * 3);
  __shared__ __align__(16) float Xsh[N_ * 3];
  __shared__ float redv[2][4];
  __shared__ int   redi[2][4];
  for (int i = t; i < (N_ * 3) / 4; i += 256)
    ((float4*)Xsh)[i] = ((const float4*)X)[i];
  __syncthreads();

  const int base = t * 16;
  float px[16], py[16], pz[16], dist[16];
#pragma unroll
  for (int j = 0; j < 16; ++j) {
    px[j] = Xsh[(base + j) * 3 + 0];
    py[j] = Xsh[(base + j) * 3 + 1];
    pz[j] = Xsh[(base + j) * 3 + 2];
    dist[j] = 1e10f;
  }
  float cx = Xsh[0], cy = Xsh[1], cz = Xsh[2];
  float* nx = out_newxyz + (size_t)b * (NPOINT_ * 3);
  float* nf = out_fpsf + (size_t)b * NPOINT_;
  if (t == 0) { nx[0] = cx; nx[1] = cy; nx[2] = cz; nf[0] = 0.f; }

  for (int it = 1; it < NPOINT_; ++it) {
    float bestv = -1.f; int besti = 0;
    {
#pragma clang fp contract(off)
#pragma unroll
      for (int j = 0; j < 16; ++j) {
        float dx = px[j] - cx, dy = py[j] - cy, dz = pz[j] - cz;
        float t0 = dx * dx, t1 = dy * dy, t2 = dz * dz;
        float d = (t0 + t1) + t2;
        float nd = fminf(dist[j], d);
        dist[j] = nd;
        bool g = nd > bestv;
        bestv = g ? nd : bestv;
        besti = g ? (base + j) : besti;
      }
    }
    // wave argmax (64 lanes), tie -> lower index
#pragma unroll
    for (int off = 1; off < 64; off <<= 1) {
      float ov = __shfl_xor(bestv, off);
      int   oi = __shfl_xor(besti, off);
      bool take = (ov > bestv) || (ov == bestv && oi < besti);
      bestv = take ? ov : bestv;
      besti = take ? oi : besti;
    }
    int par = it & 1;
    if ((t & 63) == 0) { redv[par][t >> 6] = bestv; redi[par][t >> 6] = besti; }
    __syncthreads();
    // every thread reduces the 4 wave winners (broadcast LDS reads)
    float wv = redv[par][0]; int wi = redi[par][0];
#pragma unroll
    for (int w = 1; w < 4; ++w) {
      float v = redv[par][w]; int i2 = redi[par][w];
      bool take = (v > wv) || (v == wv && i2 < wi);
      wv = take ? v : wv;
      wi = take ? i2 : wi;
    }
    cx = Xsh[wi * 3 + 0]; cy = Xsh[wi * 3 + 1]; cz = Xsh[wi * 3 + 2];
    if (t == 0) {
      nx[it * 3 + 0] = cx; nx[it * 3 + 1] = cy; nx[it * 3 + 2] = cz;
      nf[it] = (float)wi;
    }
  }
}

// ---------------- K2: ball query = first NSAMPLE in-radius indices in ascending order
__global__ __launch_bounds__(256) void k_ballq(
    const float* __restrict__ xyz, const float* __restrict__ newxyz,
    int* __restrict__ bidx) {
#pragma clang fp contract(off)
  int lane = threadIdx.x & 63;
  int s = blockIdx.x * 4 + (threadIdx.x >> 6);   // global center id 0..16383
  int b = s >> 10;
  const float* X = xyz + (size_t)b * (N_ * 3);
  float cx = newxyz[(size_t)s * 3 + 0];
  float cy = newxyz[(size_t)s * 3 + 1];
  float cz = newxyz[(size_t)s * 3 + 2];
  int* outp = bidx + (size_t)s * NSAMPLE_;
  int total = 0, first = 0;
  for (int j = 0; j < N_ / 64; ++j) {
    if (total >= NSAMPLE_) break;
    int p = j * 64 + lane;
    float dx = X[p * 3 + 0] - cx, dy = X[p * 3 + 1] - cy, dz = X[p * 3 + 2] - cz;
    float t0 = dx * dx, t1 = dy * dy, t2 = dz * dz;
    float d = (t0 + t1) + t2;
    bool inb = !(d > R2_);                       // keep if sqd <= r^2
    unsigned long long mask = __ballot(inb);
    if (total == 0 && mask) first = j * 64 + (__ffsll((long long)mask) - 1);
    if (inb) {
      int slot = total + __popcll(mask & ((1ull << lane) - 1ull));
      if (slot < NSAMPLE_) outp[slot] = p;
    }
    total += (int)__popcll(mask);
  }
  for (int slot = total + lane; slot < NSAMPLE_; slot += 64) outp[slot] = first;
}

// ---------------- K3: fused gather + collapsed-affine GEMM + k-max
// Block: 256 threads, tile = 4 centers (N=128 cols), M=128 rows, K=67.
__global__ __launch_bounds__(256) void k_mlp(
    const float* __restrict__ xyz, const float* __restrict__ feat,
    const float* __restrict__ newxyz, const int* __restrict__ bidx,
    const float* __restrict__ Wt, const float* __restrict__ beff,
    float* __restrict__ outF) {
  __shared__ __align__(16) float Wsh[CIN_][COUT_];     // [c][o]
  __shared__ float gsh[128][69];                       // [n][c], pad 69 (conflict-free)
  __shared__ int   idxs[128];
  __shared__ float ctr[4][3];
  __shared__ float bsh[COUT_];
  __shared__ float outsh[COUT_][5];
  int t = threadIdx.x;
  int b = blockIdx.y;
  int sbase = blockIdx.x * 4;

  if (t < 128) idxs[t] = bidx[((size_t)(b * NPOINT_ + sbase)) * NSAMPLE_ + t];
  if (t < 12)  ((float*)ctr)[t] = newxyz[((size_t)(b * NPOINT_ + sbase)) * 3 + t];
  if (t < COUT_) bsh[t] = beff[t];
  for (int i = t; i < (CIN_ * COUT_) / 4; i += 256)
    ((float4*)Wsh)[i] = ((const float4*)Wt)[i];
  __syncthreads();

  // gather grouped features: n = si*32 + k, channel c (0..2 rel-xyz, 3..66 feat)
  for (int i = t; i < 128 * CIN_; i += 256) {
    int n = i / CIN_, c = i - n * CIN_;
    int p = idxs[n];
    float v;
    if (c < 3) v = xyz[((size_t)b * N_ + p) * 3 + c] - ctr[n >> 5][c];
    else       v = feat[((size_t)b * N_ + p) * CFEAT_ + (c - 3)];
    gsh[n][c] = v;
  }
  __syncthreads();

  int tr = t & 15, tc = t >> 4;
  int o0 = tr * 8, n0 = tc * 8;
  float acc[8][8];
#pragma unroll
  for (int o = 0; o < 8; ++o)
#pragma unroll
    for (int q = 0; q < 8; ++q) acc[o][q] = 0.f;

  for (int c = 0; c < CIN_; ++c) {
    float4 w0 = *(const float4*)&Wsh[c][o0];
    float4 w1 = *(const float4*)&Wsh[c][o0 + 4];
    float wreg[8] = {w0.x, w0.y, w0.z, w0.w, w1.x, w1.y, w1.z, w1.w};
    float greg[8];
#pragma unroll
    for (int q = 0; q < 8; ++q) greg[q] = gsh[n0 + q][c];
#pragma unroll
    for (int o = 0; o < 8; ++o)
#pragma unroll
      for (int q = 0; q < 8; ++q)
        acc[o][q] = fmaf(wreg[o], greg[q], acc[o][q]);
  }

  // max over this thread's 8 k's, then across the 4 threads sharing (tr, si)
  int si = tc >> 2, u = tc & 3;
  float m[8];
#pragma unroll
  for (int o = 0; o < 8; ++o) {
    float a0 = fmaxf(fmaxf(acc[o][0], acc[o][1]), fmaxf(acc[o][2], acc[o][3]));
    float a1 = fmaxf(fmaxf(acc[o][4], acc[o][5]), fmaxf(acc[o][6], acc[o][7]));
    m[o] = fmaxf(a0, a1);
  }
#pragma unroll
  for (int o = 0; o < 8; ++o) {
    m[o] = fmaxf(m[o], __shfl_xor(m[o], 16));
    m[o] = fmaxf(m[o], __shfl_xor(m[o], 32));
  }
  if (u == 0) {
#pragma unroll
    for (int o = 0; o < 8; ++o) outsh[o0 + o][si] = m[o] + bsh[o0 + o];
  }
  __syncthreads();
  if (t < COUT_) {
    float4 v = make_float4(outsh[t][0], outsh[t][1], outsh[t][2], outsh[t][3]);
    *(float4*)&outF[((size_t)b * COUT_ + t) * NPOINT_ + sbase] = v;
  }
}

extern "C" void kernel_launch(void* const* d_in, const int* in_sizes, int n_in,
                              void* d_out, int out_size, void* d_ws, size_t ws_size,
                              hipStream_t stream) {
  (void)in_sizes; (void)n_in; (void)out_size; (void)ws_size;
  const float* xyz  = (const float*)d_in[0];
  const float* feat = (const float*)d_in[1];
  const float* W1 = (const float*)d_in[2];
  const float* b1 = (const float*)d_in[3];
  const float* W2 = (const float*)d_in[4];
  const float* b2 = (const float*)d_in[5];
  const float* W3 = (const float*)d_in[6];
  const float* b3 = (const float*)d_in[7];

  float* out = (float*)d_out;
  float* out_newxyz = out;                                        // 16*1024*3
  float* out_feat   = out + (size_t)B_ * NPOINT_ * 3;             // 16*128*1024
  float* out_fpsf   = out_feat + (size_t)B_ * COUT_ * NPOINT_;    // 16*1024

  char* ws = (char*)d_ws;
  int*   bidx = (int*)ws;                                         // 16*1024*32*4 = 2 MB
  float* Wt   = (float*)(ws + (size_t)B_ * NPOINT_ * NSAMPLE_ * 4);
  float* beff = Wt + CIN_ * COUT_;

  k_fuse<<<1, 256, 0, stream>>>(W1, b1, W2, b2, W3, b3, Wt, beff);
  k_fps<<<B_, 256, 0, stream>>>(xyz, out_newxyz, out_fpsf);
  k_ballq<<<(B_ * NPOINT_) / 4, 256, 0, stream>>>(xyz, out_newxyz, bidx);
  k_mlp<<<dim3(NPOINT_ / 4, B_), 256, 0, stream>>>(xyz, feat, out_newxyz, bidx, Wt, beff, out_feat);
}

// Round 3
// 1087.680 us; speedup vs baseline: 1.2268x; 1.2268x over previous
//
#include <hip/hip_runtime.h>
#include <cstdint>
#include <cstddef>

#define B_      16
#define N_      4096
#define CFEAT_  64
#define NPOINT_ 1024
#define NSAMPLE_ 32
#define CIN_    67
#define COUT_   128
#define R2_     0.04f

// ---------------- K0: collapse the 3 linear layers (no activation between them)
__global__ __launch_bounds__(256) void k_fuse(
    const float* __restrict__ W1, const float* __restrict__ b1,
    const float* __restrict__ W2, const float* __restrict__ b2,
    const float* __restrict__ W3, const float* __restrict__ b3,
    float* __restrict__ Wt /*[CIN][COUT] transposed*/, float* __restrict__ beff /*[COUT]*/) {
  __shared__ float W21[64][CIN_];
  __shared__ float b21[64];
  int t = threadIdx.x;
  for (int i = t; i < 64 * CIN_; i += 256) {
    int o = i / CIN_, c = i - o * CIN_;
    float s = 0.f;
    for (int j = 0; j < 64; ++j) s = fmaf(W2[o * 64 + j], W1[j * CIN_ + c], s);
    W21[o][c] = s;
  }
  if (t < 64) {
    float s = b2[t];
    for (int j = 0; j < 64; ++j) s = fmaf(W2[t * 64 + j], b1[j], s);
    b21[t] = s;
  }
  __syncthreads();
  for (int i = t; i < COUT_ * CIN_; i += 256) {
    int o = i / CIN_, c = i - o * CIN_;
    float s = 0.f;
    for (int j = 0; j < 64; ++j) s = fmaf(W3[o * 64 + j], W21[j][c], s);
    Wt[c * COUT_ + o] = s;   // store transposed [c][o]
  }
  if (t < COUT_) {
    float s = b3[t];
    for (int j = 0; j < 64; ++j) s = fmaf(W3[t * 64 + j], b21[j], s);
    beff[t] = s;
  }
}

// DPP-based wave max step: v = max(v, lane-permuted v). VALU-pipe, no LDS latency.
template<int CTRL>
__device__ __forceinline__ float dpp_fmax(float v) {
  int s = __builtin_amdgcn_update_dpp(__float_as_int(v), __float_as_int(v),
                                      CTRL, 0xF, 0xF, false);
  return fmaxf(v, __int_as_float(s));
}

// ---------------- K1: farthest point sampling, 1 block per batch
// Numerics must match XLA: d = (dx*dx + dy*dy) + dz*dz, NO fma contraction,
// argmax = first (lowest) index of max, dist = fminf(dist, d).
__global__ __launch_bounds__(256) void k_fps(
    const float* __restrict__ xyz,
    float* __restrict__ out_newxyz, float* __restrict__ out_fpsf) {
  int b = blockIdx.x, t = threadIdx.x;
  const float* X = xyz + (size_t)b * (N_ * 3);
  __shared__ __align__(16) float Xsh[N_ * 3];     // 48 KB
  __shared__ __align__(16) float4 res[NPOINT_];   // 16 KB (x,y,z,idx)
  __shared__ __align__(16) float redp[2][8];      // (val,idx) x 4 waves, double-buffered
  for (int i = t; i < (N_ * 3) / 4; i += 256)
    ((float4*)Xsh)[i] = ((const float4*)X)[i];
  __syncthreads();

  const int base = t * 16;
  float px[16], py[16], pz[16], dist[16];
#pragma unroll
  for (int j = 0; j < 16; ++j) {
    px[j] = Xsh[(base + j) * 3 + 0];
    py[j] = Xsh[(base + j) * 3 + 1];
    pz[j] = Xsh[(base + j) * 3 + 2];
    dist[j] = 1e10f;
  }
  float cx = Xsh[0], cy = Xsh[1], cz = Xsh[2];
  if (t == 0) res[0] = make_float4(cx, cy, cz, 0.f);

  for (int it = 1; it < NPOINT_; ++it) {
    // --- dist update (exact XLA op order, no contraction), independent per point
    {
#pragma clang fp contract(off)
#pragma unroll
      for (int j = 0; j < 16; ++j) {
        float dx = px[j] - cx, dy = py[j] - cy, dz = pz[j] - cz;
        float t0 = dx * dx, t1 = dy * dy, t2 = dz * dz;
        float d = (t0 + t1) + t2;
        dist[j] = fminf(dist[j], d);
      }
    }
    // --- tree argmax over the 16 local dists (strict > => lowest index wins ties)
    float v8[8]; int i8[8];
#pragma unroll
    for (int j = 0; j < 8; ++j) {
      bool g = dist[2 * j + 1] > dist[2 * j];
      v8[j] = g ? dist[2 * j + 1] : dist[2 * j];
      i8[j] = g ? 2 * j + 1 : 2 * j;
    }
    float v4[4]; int i4[4];
#pragma unroll
    for (int j = 0; j < 4; ++j) {
      bool g = v4[0], gg = false; (void)g; (void)gg;
      bool take = v8[2 * j + 1] > v8[2 * j];
      v4[j] = take ? v8[2 * j + 1] : v8[2 * j];
      i4[j] = take ? i8[2 * j + 1] : i8[2 * j];
    }
    float v2[2]; int i2a[2];
#pragma unroll
    for (int j = 0; j < 2; ++j) {
      bool take = v4[2 * j + 1] > v4[2 * j];
      v2[j] = take ? v4[2 * j + 1] : v4[2 * j];
      i2a[j] = take ? i4[2 * j + 1] : i4[2 * j];
    }
    bool gt = v2[1] > v2[0];
    float bv = gt ? v2[1] : v2[0];
    int bi = base + (gt ? i2a[1] : i2a[0]);

    // --- wave max via DPP (lanes 48..63 end with full-wave max)
    float v = bv;
    v = dpp_fmax<0xB1>(v);    // quad_perm(1,0,3,2)  xor1
    v = dpp_fmax<0x4E>(v);    // quad_perm(2,3,0,1)  xor2
    v = dpp_fmax<0x141>(v);   // row_half_mirror -> 8-lane max
    v = dpp_fmax<0x140>(v);   // row_mirror      -> 16-lane max
    v = dpp_fmax<0x142>(v);   // row_bcast15
    v = dpp_fmax<0x143>(v);   // row_bcast31
    float wmax = __int_as_float(__builtin_amdgcn_readlane(__float_as_int(v), 63));
    unsigned long long msk = __ballot(bv == wmax);
    int winlane = __ffsll((long long)msk) - 1;   // lowest lane = lowest index
    int wbi = __builtin_amdgcn_readlane(bi, winlane);

    // --- cross-wave reduce through LDS (4 candidates), 1 barrier/iter
    int par = it & 1;
    if ((t & 63) == 0) {
      int w = t >> 6;
      *(float2*)&redp[par][2 * w] = make_float2(wmax, __int_as_float(wbi));
    }
    __syncthreads();
    float4 r0 = *(float4*)&redp[par][0];
    float4 r1 = *(float4*)&redp[par][4];
    float wv = r0.x; int wi = __float_as_int(r0.y);
    if (r0.z > wv) { wv = r0.z; wi = __float_as_int(r0.w); }
    if (r1.x > wv) { wv = r1.x; wi = __float_as_int(r1.y); }
    if (r1.z > wv) { wv = r1.z; wi = __float_as_int(r1.w); }
    cx = Xsh[wi * 3 + 0]; cy = Xsh[wi * 3 + 1]; cz = Xsh[wi * 3 + 2];
    if (t == 0) res[it] = make_float4(cx, cy, cz, (float)wi);
  }
  __syncthreads();
  float* nx = out_newxyz + (size_t)b * (NPOINT_ * 3);
  float* nf = out_fpsf + (size_t)b * NPOINT_;
  for (int i = t; i < NPOINT_; i += 256) {
    float4 r = res[i];
    nx[i * 3 + 0] = r.x; nx[i * 3 + 1] = r.y; nx[i * 3 + 2] = r.z;
    nf[i] = r.w;
  }
}

// ---------------- K2: ball query = first NSAMPLE in-radius indices in ascending order
__global__ __launch_bounds__(256) void k_ballq(
    const float* __restrict__ xyz, const float* __restrict__ newxyz,
    int* __restrict__ bidx) {
#pragma clang fp contract(off)
  int lane = threadIdx.x & 63;
  int s = blockIdx.x * 4 + (threadIdx.x >> 6);   // global center id 0..16383
  int b = s >> 10;
  const float* X = xyz + (size_t)b * (N_ * 3);
  float cx = newxyz[(size_t)s * 3 + 0];
  float cy = newxyz[(size_t)s * 3 + 1];
  float cz = newxyz[(size_t)s * 3 + 2];
  int* outp = bidx + (size_t)s * NSAMPLE_;
  int total = 0, first = 0;
  for (int j = 0; j < N_ / 64; ++j) {
    if (total >= NSAMPLE_) break;
    int p = j * 64 + lane;
    float dx = X[p * 3 + 0] - cx, dy = X[p * 3 + 1] - cy, dz = X[p * 3 + 2] - cz;
    float t0 = dx * dx, t1 = dy * dy, t2 = dz * dz;
    float d = (t0 + t1) + t2;
    bool inb = !(d > R2_);                       // keep if sqd <= r^2
    unsigned long long mask = __ballot(inb);
    if (total == 0 && mask) first = j * 64 + (__ffsll((long long)mask) - 1);
    if (inb) {
      int slot = total + __popcll(mask & ((1ull << lane) - 1ull));
      if (slot < NSAMPLE_) outp[slot] = p;
    }
    total += (int)__popcll(mask);
  }
  for (int slot = total + lane; slot < NSAMPLE_; slot += 64) outp[slot] = first;
}

// ---------------- K3: fused gather + collapsed-affine GEMM + k-max
// Block: 256 threads, tile = 4 centers (N=128 cols), M=128 rows, K=67.
__global__ __launch_bounds__(256) void k_mlp(
    const float* __restrict__ xyz, const float* __restrict__ feat,
    const float* __restrict__ newxyz, const int* __restrict__ bidx,
    const float* __restrict__ Wt, const float* __restrict__ beff,
    float* __restrict__ outF) {
  __shared__ __align__(16) float Wsh[CIN_][COUT_];     // [c][o]
  __shared__ __align__(16) float gsh[CIN_][132];       // [c][n], pad 132
  __shared__ int   idxs[128];
  __shared__ float ctr[4][3];
  __shared__ float bsh[COUT_];
  __shared__ float outsh[COUT_][5];
  int t = threadIdx.x;
  int b = blockIdx.y;
  int sbase = blockIdx.x * 4;

  if (t < 128) idxs[t] = bidx[((size_t)(b * NPOINT_ + sbase)) * NSAMPLE_ + t];
  if (t < 12)  ((float*)ctr)[t] = newxyz[((size_t)(b * NPOINT_ + sbase)) * 3 + t];
  if (t < COUT_) bsh[t] = beff[t];
  for (int i = t; i < (CIN_ * COUT_) / 4; i += 256)
    ((float4*)Wsh)[i] = ((const float4*)Wt)[i];
  __syncthreads();

  // gather grouped features: n = si*32 + k, channel c (0..2 rel-xyz, 3..66 feat)
  for (int i = t; i < 128 * CIN_; i += 256) {
    int n = i / CIN_, c = i - n * CIN_;
    int p = idxs[n];
    float v;
    if (c < 3) v = xyz[((size_t)b * N_ + p) * 3 + c] - ctr[n >> 5][c];
    else       v = feat[((size_t)b * N_ + p) * CFEAT_ + (c - 3)];
    gsh[c][n] = v;
  }
  __syncthreads();

  int tr = t & 15, tc = t >> 4;
  int o0 = tr * 8, n0 = tc * 8;
  float acc[8][8];
#pragma unroll
  for (int o = 0; o < 8; ++o)
#pragma unroll
    for (int q = 0; q < 8; ++q) acc[o][q] = 0.f;

  for (int c = 0; c < CIN_; ++c) {
    float4 w0 = *(const float4*)&Wsh[c][o0];
    float4 w1 = *(const float4*)&Wsh[c][o0 + 4];
    float4 g0 = *(const float4*)&gsh[c][n0];
    float4 g1 = *(const float4*)&gsh[c][n0 + 4];
    float wreg[8] = {w0.x, w0.y, w0.z, w0.w, w1.x, w1.y, w1.z, w1.w};
    float greg[8] = {g0.x, g0.y, g0.z, g0.w, g1.x, g1.y, g1.z, g1.w};
#pragma unroll
    for (int o = 0; o < 8; ++o)
#pragma unroll
      for (int q = 0; q < 8; ++q)
        acc[o][q] = fmaf(wreg[o], greg[q], acc[o][q]);
  }

  // max over this thread's 8 k's, then across the 4 threads sharing (tr, si)
  int si = tc >> 2, u = tc & 3;
  float m[8];
#pragma unroll
  for (int o = 0; o < 8; ++o) {
    float a0 = fmaxf(fmaxf(acc[o][0], acc[o][1]), fmaxf(acc[o][2], acc[o][3]));
    float a1 = fmaxf(fmaxf(acc[o][4], acc[o][5]), fmaxf(acc[o][6], acc[o][7]));
    m[o] = fmaxf(a0, a1);
  }
#pragma unroll
  for (int o = 0; o < 8; ++o) {
    m[o] = fmaxf(m[o], __shfl_xor(m[o], 16));
    m[o] = fmaxf(m[o], __shfl_xor(m[o], 32));
  }
  if (u == 0) {
#pragma unroll
    for (int o = 0; o < 8; ++o) outsh[o0 + o][si] = m[o] + bsh[o0 + o];
  }
  __syncthreads();
  if (t < COUT_) {
    float4 v = make_float4(outsh[t][0], outsh[t][1], outsh[t][2], outsh[t][3]);
    *(float4*)&outF[((size_t)b * COUT_ + t) * NPOINT_ + sbase] = v;
  }
}

extern "C" void kernel_launch(void* const* d_in, const int* in_sizes, int n_in,
                              void* d_out, int out_size, void* d_ws, size_t ws_size,
                              hipStream_t stream) {
  (void)in_sizes; (void)n_in; (void)out_size; (void)ws_size;
  const float* xyz  = (const float*)d_in[0];
  const float* feat = (const float*)d_in[1];
  const float* W1 = (const float*)d_in[2];
  const float* b1 = (const float*)d_in[3];
  const float* W2 = (const float*)d_in[4];
  const float* b2 = (const float*)d_in[5];
  const float* W3 = (const float*)d_in[6];
  const float* b3 = (const float*)d_in[7];

  float* out = (float*)d_out;
  float* out_newxyz = out;                                        // 16*1024*3
  float* out_feat   = out + (size_t)B_ * NPOINT_ * 3;             // 16*128*1024
  float* out_fpsf   = out_feat + (size_t)B_ * COUT_ * NPOINT_;    // 16*1024

  char* ws = (char*)d_ws;
  int*   bidx = (int*)ws;                                         // 16*1024*32*4 = 2 MB
  float* Wt   = (float*)(ws + (size_t)B_ * NPOINT_ * NSAMPLE_ * 4);
  float* beff = Wt + CIN_ * COUT_;

  k_fuse<<<1, 256, 0, stream>>>(W1, b1, W2, b2, W3, b3, Wt, beff);
  k_fps<<<B_, 256, 0, stream>>>(xyz, out_newxyz, out_fpsf);
  k_ballq<<<(B_ * NPOINT_) / 4, 256, 0, stream>>>(xyz, out_newxyz, bidx);
  k_mlp<<<dim3(NPOINT_ / 4, B_), 256, 0, stream>>>(xyz, feat, out_newxyz, bidx, Wt, beff, out_feat);
}

// Round 4
// 956.478 us; speedup vs baseline: 1.3951x; 1.1372x over previous
//
#include <hip/hip_runtime.h>
#include <cstdint>
#include <cstddef>

#define B_      16
#define N_      4096
#define CFEAT_  64
#define NPOINT_ 1024
#define NSAMPLE_ 32
#define CIN_    67
#define COUT_   128
#define R2_     0.04f

typedef float f32x2 __attribute__((ext_vector_type(2)));

// Packed f32 ops (VOP3P). Elementwise IEEE-identical to scalar; sub = add(-b).
__device__ __forceinline__ f32x2 pk_sub(f32x2 a, f32x2 b) {
  f32x2 d;
  asm("v_pk_add_f32 %0, %1, %2 neg_lo:[0,1] neg_hi:[0,1]" : "=v"(d) : "v"(a), "v"(b));
  return d;
}
__device__ __forceinline__ f32x2 pk_mul(f32x2 a, f32x2 b) {
  f32x2 d;
  asm("v_pk_mul_f32 %0, %1, %2" : "=v"(d) : "v"(a), "v"(b));
  return d;
}
__device__ __forceinline__ f32x2 pk_add(f32x2 a, f32x2 b) {
  f32x2 d;
  asm("v_pk_add_f32 %0, %1, %2" : "=v"(d) : "v"(a), "v"(b));
  return d;
}
__device__ __forceinline__ float max3f(float a, float b, float c) {
  float r;
  asm("v_max3_f32 %0, %1, %2, %3" : "=v"(r) : "v"(a), "v"(b), "v"(c));
  return r;
}

// DPP-based wave max step: v = max(v, lane-permuted v). VALU-pipe, no LDS latency.
template<int CTRL>
__device__ __forceinline__ float dpp_fmax(float v) {
  int s = __builtin_amdgcn_update_dpp(__float_as_int(v), __float_as_int(v),
                                      CTRL, 0xF, 0xF, false);
  return fmaxf(v, __int_as_float(s));
}

// ---------------- K0: collapse the 3 linear layers (no activation between them)
__global__ __launch_bounds__(256) void k_fuse(
    const float* __restrict__ W1, const float* __restrict__ b1,
    const float* __restrict__ W2, const float* __restrict__ b2,
    const float* __restrict__ W3, const float* __restrict__ b3,
    float* __restrict__ Wt /*[CIN][COUT] transposed*/, float* __restrict__ beff /*[COUT]*/) {
  __shared__ float W21[64][CIN_];
  __shared__ float b21[64];
  int t = threadIdx.x;
  for (int i = t; i < 64 * CIN_; i += 256) {
    int o = i / CIN_, c = i - o * CIN_;
    float s = 0.f;
    for (int j = 0; j < 64; ++j) s = fmaf(W2[o * 64 + j], W1[j * CIN_ + c], s);
    W21[o][c] = s;
  }
  if (t < 64) {
    float s = b2[t];
    for (int j = 0; j < 64; ++j) s = fmaf(W2[t * 64 + j], b1[j], s);
    b21[t] = s;
  }
  __syncthreads();
  for (int i = t; i < COUT_ * CIN_; i += 256) {
    int o = i / CIN_, c = i - o * CIN_;
    float s = 0.f;
    for (int j = 0; j < 64; ++j) s = fmaf(W3[o * 64 + j], W21[j][c], s);
    Wt[c * COUT_ + o] = s;   // store transposed [c][o]
  }
  if (t < COUT_) {
    float s = b3[t];
    for (int j = 0; j < 64; ++j) s = fmaf(W3[t * 64 + j], b21[j], s);
    beff[t] = s;
  }
}

// ---------------- K1: farthest point sampling, 1 block per batch
// Numerics must match XLA: d = (dx*dx + dy*dy) + dz*dz, NO fma contraction,
// argmax = first (lowest) index of max, dist = fminf(dist, d).
__global__ __launch_bounds__(256) void k_fps(
    const float* __restrict__ xyz,
    float* __restrict__ out_newxyz, float* __restrict__ out_fpsf) {
  int b = blockIdx.x, t = threadIdx.x;
  const float* X = xyz + (size_t)b * (N_ * 3);
  __shared__ __align__(16) float Xsh[N_ * 3];     // 48 KB
  __shared__ __align__(16) float4 res[NPOINT_];   // 16 KB (x,y,z,idx)
  __shared__ __align__(16) float4 redA[2][4];     // (val,x,y,z) per wave, dbuf
  __shared__ __align__(16) int    redI[2][4];     // idx per wave
  for (int i = t; i < (N_ * 3) / 4; i += 256)
    ((float4*)Xsh)[i] = ((const float4*)X)[i];
  __syncthreads();

  const int base = t * 16;
  f32x2 px[8], py[8], pz[8], dist[8];
#pragma unroll
  for (int k = 0; k < 8; ++k) {
    int j = base + 2 * k;
    px[k] = f32x2{Xsh[j * 3 + 0], Xsh[j * 3 + 3]};
    py[k] = f32x2{Xsh[j * 3 + 1], Xsh[j * 3 + 4]};
    pz[k] = f32x2{Xsh[j * 3 + 2], Xsh[j * 3 + 5]};
    dist[k] = f32x2{1e10f, 1e10f};
  }
  float cx = Xsh[0], cy = Xsh[1], cz = Xsh[2];
  if (t == 0) res[0] = make_float4(cx, cy, cz, 0.f);
  const int w = t >> 6, lane = t & 63;

  for (int it = 1; it < NPOINT_; ++it) {
    // --- dist update: packed, exact XLA op order ((dx^2+dy^2)+dz^2), min
    f32x2 cxx = {cx, cx}, cyy = {cy, cy}, czz = {cz, cz};
    {
#pragma clang fp contract(off)
#pragma unroll
      for (int k = 0; k < 8; ++k) {
        f32x2 dx = pk_sub(px[k], cxx);
        f32x2 dy = pk_sub(py[k], cyy);
        f32x2 dz = pk_sub(pz[k], czz);
        f32x2 s = pk_add(pk_add(pk_mul(dx, dx), pk_mul(dy, dy)), pk_mul(dz, dz));
        dist[k].x = fminf(dist[k].x, s.x);
        dist[k].y = fminf(dist[k].y, s.y);
      }
    }
    // --- value-only max over 16 via v_max3 tree (critical path: 8 instr)
    float m0 = max3f(dist[0].x, dist[0].y, dist[1].x);
    float m1 = max3f(dist[1].y, dist[2].x, dist[2].y);
    float m2 = max3f(dist[3].x, dist[3].y, dist[4].x);
    float m3 = max3f(dist[4].y, dist[5].x, dist[5].y);
    float m4 = max3f(dist[6].x, dist[6].y, dist[7].x);
    float n0 = max3f(m0, m1, m2);
    float n1 = max3f(m3, m4, dist[7].y);
    float bv = fmaxf(n0, n1);

    // --- index recovery (off critical path; lowest j with dist==bv)
    int jm = 15;
#pragma unroll
    for (int j = 14; j >= 0; --j) {
      float dj = (j & 1) ? dist[j >> 1].y : dist[j >> 1].x;
      jm = (dj == bv) ? j : jm;
    }
    int bi = base + jm;

    // --- wave max via DPP (lane 63 ends with full-wave max)
    float v = bv;
    v = dpp_fmax<0xB1>(v);    // quad_perm(1,0,3,2)
    v = dpp_fmax<0x4E>(v);    // quad_perm(2,3,0,1)
    v = dpp_fmax<0x141>(v);   // row_half_mirror
    v = dpp_fmax<0x140>(v);   // row_mirror
    v = dpp_fmax<0x142>(v);   // row_bcast15
    v = dpp_fmax<0x143>(v);   // row_bcast31
    float wmax = __int_as_float(__builtin_amdgcn_readlane(__float_as_int(v), 63));
    unsigned long long msk = __ballot(bv == wmax);
    int winlane = __ffsll((long long)msk) - 1;   // lowest lane = lowest index
    int wbi = __builtin_amdgcn_readlane(bi, winlane);

    // --- cross-wave reduce; leaders fetch own candidate coords pre-barrier
    int par = it & 1;
    if (lane == 0) {
      float x = Xsh[wbi * 3 + 0], y = Xsh[wbi * 3 + 1], z = Xsh[wbi * 3 + 2];
      redA[par][w] = make_float4(wmax, x, y, z);
      redI[par][w] = wbi;
    }
    __syncthreads();
    float4 a0 = redA[par][0], a1 = redA[par][1];
    float4 a2 = redA[par][2], a3 = redA[par][3];
    int4 ii = *(const int4*)&redI[par][0];
    bool g01 = a1.x > a0.x, g23 = a3.x > a2.x;
    float4 s01 = g01 ? a1 : a0; int i01 = g01 ? ii.y : ii.x;
    float4 s23 = g23 ? a3 : a2; int i23 = g23 ? ii.w : ii.z;
    bool g = s23.x > s01.x;
    float4 s = g ? s23 : s01; int wi = g ? i23 : i01;
    cx = s.y; cy = s.z; cz = s.w;
    if (t == 0) res[it] = make_float4(cx, cy, cz, (float)wi);
  }
  __syncthreads();
  float* nx = out_newxyz + (size_t)b * (NPOINT_ * 3);
  float* nf = out_fpsf + (size_t)b * NPOINT_;
  for (int i = t; i < NPOINT_; i += 256) {
    float4 r = res[i];
    nx[i * 3 + 0] = r.x; nx[i * 3 + 1] = r.y; nx[i * 3 + 2] = r.z;
    nf[i] = r.w;
  }
}

// ---------------- K2: ball query = first NSAMPLE in-radius indices in ascending order
__global__ __launch_bounds__(256) void k_ballq(
    const float* __restrict__ xyz, const float* __restrict__ newxyz,
    int* __restrict__ bidx) {
#pragma clang fp contract(off)
  int lane = threadIdx.x & 63;
  int s = blockIdx.x * 4 + (threadIdx.x >> 6);   // global center id 0..16383
  int b = s >> 10;
  const float* X = xyz + (size_t)b * (N_ * 3);
  float cx = newxyz[(size_t)s * 3 + 0];
  float cy = newxyz[(size_t)s * 3 + 1];
  float cz = newxyz[(size_t)s * 3 + 2];
  int* outp = bidx + (size_t)s * NSAMPLE_;
  int total = 0, first = 0;
  for (int j = 0; j < N_ / 64; ++j) {
    if (total >= NSAMPLE_) break;
    int p = j * 64 + lane;
    float dx = X[p * 3 + 0] - cx, dy = X[p * 3 + 1] - cy, dz = X[p * 3 + 2] - cz;
    float t0 = dx * dx, t1 = dy * dy, t2 = dz * dz;
    float d = (t0 + t1) + t2;
    bool inb = !(d > R2_);                       // keep if sqd <= r^2
    unsigned long long mask = __ballot(inb);
    if (total == 0 && mask) first = j * 64 + (__ffsll((long long)mask) - 1);
    if (inb) {
      int slot = total + __popcll(mask & ((1ull << lane) - 1ull));
      if (slot < NSAMPLE_) outp[slot] = p;
    }
    total += (int)__popcll(mask);
  }
  for (int slot = total + lane; slot < NSAMPLE_; slot += 64) outp[slot] = first;
}

// ---------------- K3: fused gather + collapsed-affine GEMM + k-max
// Block: 256 threads, tile = 4 centers (N=128 cols), M=128 rows, K=67.
__global__ __launch_bounds__(256) void k_mlp(
    const float* __restrict__ xyz, const float* __restrict__ feat,
    const float* __restrict__ newxyz, const int* __restrict__ bidx,
    const float* __restrict__ Wt, const float* __restrict__ beff,
    float* __restrict__ outF) {
  __shared__ __align__(16) float Wsh[CIN_][COUT_];     // [c][o]
  __shared__ __align__(16) float gsh[CIN_][132];       // [c][n], pad 132
  __shared__ int   idxs[128];
  __shared__ float ctr[4][3];
  __shared__ float bsh[COUT_];
  __shared__ float outsh[COUT_][5];
  int t = threadIdx.x;
  int b = blockIdx.y;
  int sbase = blockIdx.x * 4;

  if (t < 128) idxs[t] = bidx[((size_t)(b * NPOINT_ + sbase)) * NSAMPLE_ + t];
  if (t < 12)  ((float*)ctr)[t] = newxyz[((size_t)(b * NPOINT_ + sbase)) * 3 + t];
  if (t < COUT_) bsh[t] = beff[t];
  for (int i = t; i < (CIN_ * COUT_) / 4; i += 256)
    ((float4*)Wsh)[i] = ((const float4*)Wt)[i];
  __syncthreads();

  // gather grouped features: n = si*32 + k, channel c (0..2 rel-xyz, 3..66 feat)
  for (int i = t; i < 128 * CIN_; i += 256) {
    int n = i / CIN_, c = i - n * CIN_;
    int p = idxs[n];
    float v;
    if (c < 3) v = xyz[((size_t)b * N_ + p) * 3 + c] - ctr[n >> 5][c];
    else       v = feat[((size_t)b * N_ + p) * CFEAT_ + (c - 3)];
    gsh[c][n] = v;
  }
  __syncthreads();

  int tr = t & 15, tc = t >> 4;
  int o0 = tr * 8, n0 = tc * 8;
  float acc[8][8];
#pragma unroll
  for (int o = 0; o < 8; ++o)
#pragma unroll
    for (int q = 0; q < 8; ++q) acc[o][q] = 0.f;

  for (int c = 0; c < CIN_; ++c) {
    float4 w0 = *(const float4*)&Wsh[c][o0];
    float4 w1 = *(const float4*)&Wsh[c][o0 + 4];
    float4 g0 = *(const float4*)&gsh[c][n0];
    float4 g1 = *(const float4*)&gsh[c][n0 + 4];
    float wreg[8] = {w0.x, w0.y, w0.z, w0.w, w1.x, w1.y, w1.z, w1.w};
    float greg[8] = {g0.x, g0.y, g0.z, g0.w, g1.x, g1.y, g1.z, g1.w};
#pragma unroll
    for (int o = 0; o < 8; ++o)
#pragma unroll
      for (int q = 0; q < 8; ++q)
        acc[o][q] = fmaf(wreg[o], greg[q], acc[o][q]);
  }

  // max over this thread's 8 k's, then across the 4 threads sharing (tr, si)
  int si = tc >> 2, u = tc & 3;
  float m[8];
#pragma unroll
  for (int o = 0; o < 8; ++o) {
    float a0 = fmaxf(fmaxf(acc[o][0], acc[o][1]), fmaxf(acc[o][2], acc[o][3]));
    float a1 = fmaxf(fmaxf(acc[o][4], acc[o][5]), fmaxf(acc[o][6], acc[o][7]));
    m[o] = fmaxf(a0, a1);
  }
#pragma unroll
  for (int o = 0; o < 8; ++o) {
    m[o] = fmaxf(m[o], __shfl_xor(m[o], 16));
    m[o] = fmaxf(m[o], __shfl_xor(m[o], 32));
  }
  if (u == 0) {
#pragma unroll
    for (int o = 0; o < 8; ++o) outsh[o0 + o][si] = m[o] + bsh[o0 + o];
  }
  __syncthreads();
  if (t < COUT_) {
    float4 v = make_float4(outsh[t][0], outsh[t][1], outsh[t][2], outsh[t][3]);
    *(float4*)&outF[((size_t)b * COUT_ + t) * NPOINT_ + sbase] = v;
  }
}

extern "C" void kernel_launch(void* const* d_in, const int* in_sizes, int n_in,
                              void* d_out, int out_size, void* d_ws, size_t ws_size,
                              hipStream_t stream) {
  (void)in_sizes; (void)n_in; (void)out_size; (void)ws_size;
  const float* xyz  = (const float*)d_in[0];
  const float* feat = (const float*)d_in[1];
  const float* W1 = (const float*)d_in[2];
  const float* b1 = (const float*)d_in[3];
  const float* W2 = (const float*)d_in[4];
  const float* b2 = (const float*)d_in[5];
  const float* W3 = (const float*)d_in[6];
  const float* b3 = (const float*)d_in[7];

  float* out = (float*)d_out;
  float* out_newxyz = out;                                        // 16*1024*3
  float* out_feat   = out + (size_t)B_ * NPOINT_ * 3;             // 16*128*1024
  float* out_fpsf   = out_feat + (size_t)B_ * COUT_ * NPOINT_;    // 16*1024

  char* ws = (char*)d_ws;
  int*   bidx = (int*)ws;                                         // 16*1024*32*4 = 2 MB
  float* Wt   = (float*)(ws + (size_t)B_ * NPOINT_ * NSAMPLE_ * 4);
  float* beff = Wt + CIN_ * COUT_;

  k_fuse<<<1, 256, 0, stream>>>(W1, b1, W2, b2, W3, b3, Wt, beff);
  k_fps<<<B_, 256, 0, stream>>>(xyz, out_newxyz, out_fpsf);
  k_ballq<<<(B_ * NPOINT_) / 4, 256, 0, stream>>>(xyz, out_newxyz, bidx);
  k_mlp<<<dim3(NPOINT_ / 4, B_), 256, 0, stream>>>(xyz, feat, out_newxyz, bidx, Wt, beff, out_feat);
}